// Round 5
// baseline (285.719 us; speedup 1.0000x reference)
//
#include <hip/hip_runtime.h>
#include <stdint.h>

#define DIM 64
#define GB 128          // nodes per dst-bucket (NB = ceil(N/GB) must be <= 1024)
#define GSH 7
#define CH 4096         // edges per partition block (391 blocks @ E=1.6M)
#define TB1 512
#define BINS2 50000     // hist bins per range (u16-packed: 25000 words = 100 KB LDS)
#define RANGES 2        // ceil(100000 / 50000)
#define NSLICE 64       // edge slices for src hist
#define TBH 1024        // hist block size
#define ECAP 1024       // csr edges staged in LDS per prop block (8 KB)

// bf16 helpers: RNE pack, shift-unpack
__device__ __forceinline__ unsigned bf16rne(float f) {
    unsigned u = __float_as_uint(f);
    return (u + 0x7FFFu + ((u >> 16) & 1u)) >> 16;
}
__device__ __forceinline__ unsigned pack2(float lo, float hi) {
    return bf16rne(lo) | (bf16rne(hi) << 16);
}
#define UNPK(u, lo, hi) { lo = __uint_as_float((u) << 16); hi = __uint_as_float((u) & 0xFFFF0000u); }

// ---- outdeg histogram (u16-packed LDS -> coalesced global atomics) ------
// Also fused: dst-bucket totals (r==0 blocks).
__global__ void __launch_bounds__(TBH)
hist_src_kernel(const int* __restrict__ src, const int* __restrict__ dst,
                int* __restrict__ outdeg, int* __restrict__ bcnt,
                int E, int N, int Es, int NB) {
    __shared__ unsigned h32[BINS2 / 2];  // 100 KB
    __shared__ int hb[1024];             // dst-bucket counts (r==0 blocks only)
    const int b = blockIdx.x;
    const int r = b / NSLICE, s = b % NSLICE;
    const int base = r * BINS2;
    const int hi = min(base + BINS2, N);
    const int nbw = (hi - base + 1) >> 1;  // words (base even)
    for (int j = threadIdx.x; j < nbw; j += TBH) h32[j] = 0;
    if (r == 0) for (int j = threadIdx.x; j < NB; j += TBH) hb[j] = 0;
    __syncthreads();
    const int e0 = s * Es, e1 = min(e0 + Es, E);
    if (r == 0) {
#pragma unroll 4
        for (int i = e0 + threadIdx.x; i < e1; i += TBH) {
            unsigned j = (unsigned)(src[i] - base);
            if (j < (unsigned)BINS2) atomicAdd(&h32[j >> 1], 1u << ((j & 1) * 16));
            atomicAdd(&hb[((unsigned)dst[i]) >> GSH], 1);
        }
    } else {
#pragma unroll 4
        for (int i = e0 + threadIdx.x; i < e1; i += TBH) {
            unsigned j = (unsigned)(src[i] - base);
            if (j < (unsigned)BINS2) atomicAdd(&h32[j >> 1], 1u << ((j & 1) * 16));
        }
    }
    __syncthreads();
    // flush both u16 halves into plain u32 outdeg (L2-resident, coalesced-ish)
    for (int j = threadIdx.x; j < nbw; j += TBH) {
        unsigned v = h32[j];
        if (v) {
            unsigned lo = v & 0xFFFFu, hh = v >> 16;
            int nidx = base + 2 * j;
            if (lo) atomicAdd((unsigned*)&outdeg[nidx], lo);
            if (hh && nidx + 1 < N) atomicAdd((unsigned*)&outdeg[nidx + 1], hh);
        }
    }
    if (r == 0)
        for (int j = threadIdx.x; j < NB; j += TBH)
            if (hb[j]) atomicAdd(&bcnt[j], hb[j]);
}

// dis[i] = rsqrt(outdeg + 1)
__global__ void __launch_bounds__(256)
dis_kernel(const int* __restrict__ outdeg, float* __restrict__ dis, int N) {
    const int i = blockIdx.x * blockDim.x + threadIdx.x;
    if (i >= N) return;
    dis[i] = rsqrtf((float)outdeg[i] + 1.0f);
}

// single block: exclusive scan of bucket counts -> bases + write cursors
__global__ void scan_buckets(const int* __restrict__ bcnt, int* __restrict__ bucket_base,
                             int* __restrict__ cursor, int* __restrict__ offsets,
                             int NB, int N) {
    __shared__ int buf[1024];
    const int t = threadIdx.x;
    int v = (t < NB) ? bcnt[t] : 0;
    buf[t] = v;
    __syncthreads();
    for (int off = 1; off < 1024; off <<= 1) {
        int add = (t >= off) ? buf[t - off] : 0;
        __syncthreads();
        buf[t] += add;
        __syncthreads();
    }
    if (t < NB) { bucket_base[t] = buf[t] - v; cursor[t] = buf[t] - v; }
    if (t == NB - 1) { bucket_base[NB] = buf[t]; offsets[N] = buf[t]; }
}

// ---- phase 1: partition edges into dst-bucket-major staging -------------
// High-occupancy: 4 KB LDS, 391 blocks, raw ew stored (weights in place).
__global__ void __launch_bounds__(TB1)
part_kernel(const int* __restrict__ src, const int* __restrict__ dst,
            const float* __restrict__ ew,
            int* __restrict__ cursor, int2* __restrict__ staged, int E, int NB) {
    __shared__ int h[1024];
    const int tid = threadIdx.x;
    const int e0 = blockIdx.x * CH;
    const int e1 = min(e0 + CH, E);
    for (int j = tid; j < NB; j += TB1) h[j] = 0;
    __syncthreads();
    // pass A: histogram dst buckets, keep dst values in registers
    int4 d[CH / (TB1 * 4)];
    int ngrp = 0;
    for (int i = e0 + tid * 4, k = 0; i < e1; i += TB1 * 4, ++k) {
        int4 t;
        if (i + 3 < e1) t = *(const int4*)(dst + i);
        else {
            t.x = dst[i];
            t.y = (i + 1 < e1) ? dst[i + 1] : -1;
            t.z = (i + 2 < e1) ? dst[i + 2] : -1;
            t.w = (i + 3 < e1) ? dst[i + 3] : -1;
        }
        d[k] = t;
        if (t.x >= 0) atomicAdd(&h[t.x >> GSH], 1);
        if (t.y >= 0) atomicAdd(&h[t.y >> GSH], 1);
        if (t.z >= 0) atomicAdd(&h[t.z >> GSH], 1);
        if (t.w >= 0) atomicAdd(&h[t.w >> GSH], 1);
        ngrp = k + 1;
    }
    __syncthreads();
    // reserve contiguous runs; h becomes the block's global write cursor
    for (int j = tid; j < NB; j += TB1) {
        int c = h[j];
        h[j] = c ? atomicAdd(&cursor[j], c) : 0;
    }
    __syncthreads();
    // pass B: write packed records (src | tlocal<<20, raw ew)
    for (int i = e0 + tid * 4, k = 0; k < ngrp; i += TB1 * 4, ++k) {
        int4 t = d[k];
        int4 ss = make_int4(0, 0, 0, 0);
        float4 ww = make_float4(0.f, 0.f, 0.f, 0.f);
        if (i + 3 < e1) { ss = *(const int4*)(src + i); ww = *(const float4*)(ew + i); }
        else {
            ss.x = src[i]; ww.x = ew[i];
            if (i + 1 < e1) { ss.y = src[i + 1]; ww.y = ew[i + 1]; }
            if (i + 2 < e1) { ss.z = src[i + 2]; ww.z = ew[i + 2]; }
            if (i + 3 < e1) { ss.w = src[i + 3]; ww.w = ew[i + 3]; }
        }
#define PART1(T, S, W) if ((T) >= 0) { \
        int pos_ = atomicAdd(&h[(T) >> GSH], 1); \
        staged[pos_] = make_int2((S) | (((T) & (GB - 1)) << 20), __float_as_int(W)); }
        PART1(t.x, ss.x, ww.x)
        PART1(t.y, ss.y, ww.y)
        PART1(t.z, ss.z, ww.z)
        PART1(t.w, ss.w, ww.w)
#undef PART1
    }
}

// ---- phase 2: per-bucket placement into final CSR + offsets -------------
__global__ void __launch_bounds__(256)
place_kernel(const int2* __restrict__ staged, const int* __restrict__ bucket_base,
             const float* __restrict__ dis,
             int* __restrict__ offsets, int2* __restrict__ csr, int N) {
    __shared__ int cnt[GB];
    __shared__ int cur[GB];
    __shared__ int pre[GB + 1];
    __shared__ float disb[GB];
    const int b = blockIdx.x;
    const int n0 = b << GSH;
    const int nb = min(GB, N - n0);
    const int r0 = bucket_base[b], r1 = bucket_base[b + 1];
    for (int j = threadIdx.x; j < GB; j += 256) cnt[j] = 0;
    for (int j = threadIdx.x; j < nb; j += 256) disb[j] = dis[n0 + j];
    __syncthreads();
    for (int i = r0 + threadIdx.x; i < r1; i += 256)
        atomicAdd(&cnt[(staged[i].x >> 20) & (GB - 1)], 1);
    __syncthreads();
    if (threadIdx.x == 0) {
        int run = r0;
        for (int j = 0; j < nb; ++j) { pre[j] = run; run += cnt[j]; }
        pre[nb] = run;
    }
    __syncthreads();
    for (int j = threadIdx.x; j < nb; j += 256) { offsets[n0 + j] = pre[j]; cur[j] = pre[j]; }
    __syncthreads();
    for (int i = r0 + threadIdx.x; i < r1; i += 256) {
        int2 rec = staged[i];
        int tl = (rec.x >> 20) & (GB - 1);
        int s = rec.x & 0xFFFFF;
        int rank = atomicAdd(&cur[tl], 1);
        float w = dis[s] * __int_as_float(rec.y) * disb[tl];
        csr[rank] = make_int2(s, __float_as_int(w));
    }
}

// fp32 emb -> bf16 copy (one uint4 = 8 bf16 per thread)
__global__ void __launch_bounds__(256)
conv_kernel(const float4* __restrict__ in4, uint4* __restrict__ outb, int n8) {
    int i = blockIdx.x * blockDim.x + threadIdx.x;
    if (i >= n8) return;
    float4 a = in4[2 * i], b = in4[2 * i + 1];
    uint4 o;
    o.x = pack2(a.x, a.y); o.y = pack2(a.z, a.w);
    o.z = pack2(b.x, b.y); o.w = pack2(b.z, b.w);
    outb[i] = o;
}

// ---- propagation --------------------------------------------------------
// 8 nodes per wave; block = 32 consecutive nodes -> their csr range is one
// contiguous slice, cooperatively staged in LDS (chunked for generality).
// Removes the global-csr hop from the gather critical path.
// Last layer (outF != null) fuses the final combine.
__global__ void __launch_bounds__(256)
prop_kernel(const uint4* __restrict__ xg, const float4* __restrict__ selfF,
            uint4* __restrict__ xstore,
            const int* __restrict__ offsets, const int2* __restrict__ csr,
            const float* __restrict__ dis, int n,
            const float4* __restrict__ embF, const uint4* __restrict__ xaF,
            float4* __restrict__ outF) {
    __shared__ int2 elds[ECAP];
    const int tid = threadIdx.x;
    const int lane = tid & 63;
    const int fl  = lane & 7;
    const int sub = lane >> 3;
    const int node0 = blockIdx.x * 32;
    const int nodeL = min(node0 + 32, n);
    const int gbeg = offsets[node0];
    const int gend = offsets[nodeL];

    const int node = node0 + (tid >> 6) * 8 + sub;
    const bool active = (node < n);
    int beg = gbeg, end = gbeg;
    float d = 0.f;
    if (active) {
        beg = offsets[node];
        end = offsets[node + 1];
        d = dis[node];
    }
    const float dd = d * d;   // self-loop: norm = dis[i]^2, weight 1

    float a0 = 0, a1 = 0, a2 = 0, a3 = 0, a4 = 0, a5 = 0, a6 = 0, a7 = 0;
    uint4 qs = make_uint4(0, 0, 0, 0);   // self row (kept for fused combine)
    if (active) {
        if (selfF) {
            float4 s0 = selfF[(size_t)node * 16 + fl * 2];
            float4 s1 = selfF[(size_t)node * 16 + fl * 2 + 1];
            a0 = dd * s0.x; a1 = dd * s0.y; a2 = dd * s0.z; a3 = dd * s0.w;
            a4 = dd * s1.x; a5 = dd * s1.y; a6 = dd * s1.z; a7 = dd * s1.w;
        } else {
            qs = xg[(size_t)node * 8 + fl];
            float l, h;
            UNPK(qs.x, l, h) a0 = dd * l; a1 = dd * h;
            UNPK(qs.y, l, h) a2 = dd * l; a3 = dd * h;
            UNPK(qs.z, l, h) a4 = dd * l; a5 = dd * h;
            UNPK(qs.w, l, h) a6 = dd * l; a7 = dd * h;
        }
    }

#define EDGE(E, Q) { float w_ = __int_as_float((E).y); float l, h; \
    UNPK((Q).x, l, h) a0 = fmaf(w_, l, a0); a1 = fmaf(w_, h, a1); \
    UNPK((Q).y, l, h) a2 = fmaf(w_, l, a2); a3 = fmaf(w_, h, a3); \
    UNPK((Q).z, l, h) a4 = fmaf(w_, l, a4); a5 = fmaf(w_, h, a5); \
    UNPK((Q).w, l, h) a6 = fmaf(w_, l, a6); a7 = fmaf(w_, h, a7); }

    // chunked LDS staging of the block's csr slice (uniform control flow)
    for (int c0 = gbeg; c0 < gend; c0 += ECAP) {
        const int c1 = min(c0 + ECAP, gend);
        __syncthreads();
        for (int i = tid; i < c1 - c0; i += 256) elds[i] = csr[c0 + i];
        __syncthreads();
        int p  = (beg > c0) ? beg : c0;
        const int pe = (end < c1) ? end : c1;
        for (; p + 8 <= pe; p += 8) {
            const int q = p - c0;
            int2 e0 = elds[q + 0], e1 = elds[q + 1], e2 = elds[q + 2], e3 = elds[q + 3];
            int2 e4 = elds[q + 4], e5 = elds[q + 5], e6 = elds[q + 6], e7 = elds[q + 7];
            uint4 q0 = xg[(size_t)e0.x * 8 + fl];
            uint4 q1 = xg[(size_t)e1.x * 8 + fl];
            uint4 q2 = xg[(size_t)e2.x * 8 + fl];
            uint4 q3 = xg[(size_t)e3.x * 8 + fl];
            uint4 q4 = xg[(size_t)e4.x * 8 + fl];
            uint4 q5 = xg[(size_t)e5.x * 8 + fl];
            uint4 q6 = xg[(size_t)e6.x * 8 + fl];
            uint4 q7 = xg[(size_t)e7.x * 8 + fl];
            EDGE(e0, q0) EDGE(e1, q1) EDGE(e2, q2) EDGE(e3, q3)
            EDGE(e4, q4) EDGE(e5, q5) EDGE(e6, q6) EDGE(e7, q7)
        }
        for (; p + 4 <= pe; p += 4) {
            const int q = p - c0;
            int2 e0 = elds[q + 0], e1 = elds[q + 1], e2 = elds[q + 2], e3 = elds[q + 3];
            uint4 q0 = xg[(size_t)e0.x * 8 + fl];
            uint4 q1 = xg[(size_t)e1.x * 8 + fl];
            uint4 q2 = xg[(size_t)e2.x * 8 + fl];
            uint4 q3 = xg[(size_t)e3.x * 8 + fl];
            EDGE(e0, q0) EDGE(e1, q1) EDGE(e2, q2) EDGE(e3, q3)
        }
        for (; p < pe; ++p) {
            int2 e = elds[p - c0];
            uint4 q = xg[(size_t)e.x * 8 + fl];
            EDGE(e, q)
        }
    }
#undef EDGE

    if (!active) return;
    if (outF) {
        // fused final combine: out = 0.25*(emb + xa + xb(=qs) + xc(regs))
        float4 eA = embF[(size_t)node * 16 + fl * 2];
        float4 eB = embF[(size_t)node * 16 + fl * 2 + 1];
        uint4 qa = xaF[(size_t)node * 8 + fl];
        float r0 = eA.x + a0, r1 = eA.y + a1, r2 = eA.z + a2, r3 = eA.w + a3;
        float r4 = eB.x + a4, r5 = eB.y + a5, r6 = eB.z + a6, r7 = eB.w + a7;
        float l, h;
        UNPK(qa.x, l, h) r0 += l; r1 += h;
        UNPK(qa.y, l, h) r2 += l; r3 += h;
        UNPK(qa.z, l, h) r4 += l; r5 += h;
        UNPK(qa.w, l, h) r6 += l; r7 += h;
        UNPK(qs.x, l, h) r0 += l; r1 += h;
        UNPK(qs.y, l, h) r2 += l; r3 += h;
        UNPK(qs.z, l, h) r4 += l; r5 += h;
        UNPK(qs.w, l, h) r6 += l; r7 += h;
        outF[(size_t)node * 16 + fl * 2] =
            make_float4(0.25f * r0, 0.25f * r1, 0.25f * r2, 0.25f * r3);
        outF[(size_t)node * 16 + fl * 2 + 1] =
            make_float4(0.25f * r4, 0.25f * r5, 0.25f * r6, 0.25f * r7);
    } else {
        uint4 o;
        o.x = pack2(a0, a1); o.y = pack2(a2, a3);
        o.z = pack2(a4, a5); o.w = pack2(a6, a7);
        xstore[(size_t)node * 8 + fl] = o;
    }
}

// ---- launch -------------------------------------------------------------

extern "C" void kernel_launch(void* const* d_in, const int* in_sizes, int n_in,
                              void* d_out, int out_size, void* d_ws, size_t ws_size,
                              hipStream_t stream) {
    const float* emb = (const float*)d_in[0];   // [N, 64] fp32
    const float* ew  = (const float*)d_in[1];   // [E] fp32
    const int*   ei  = (const int*)d_in[2];     // [2, E] int32
    const int E = in_sizes[2] / 2;
    const int N = in_sizes[0] / DIM;
    const int* src = ei;        // edge_index[0] = source j
    const int* dst = ei + E;    // edge_index[1] = target i
    float* out = (float*)d_out;

    const int NB = (N + GB - 1) >> GSH;   // dst buckets (782 @ N=100k)
    const int Es = (E + NSLICE - 1) / NSLICE;

    // workspace (~40 MB). Alias: staged (dead after place) ⊕ xb (first
    // written in prop L2).
    char* w = (char*)d_ws;
    size_t xSz = ((size_t)N * DIM * 2 + 255) & ~(size_t)255;       // 12.8 MB
    size_t sSz = ((size_t)E * 8 + 255) & ~(size_t)255;             // 12.8 MB
    size_t uSz = xSz > sSz ? xSz : sSz;
    int2* staged = (int2*)w;
    uint4* xb    = (uint4*)w; w += uSz;
    int2* csr    = (int2*)w; w += sSz;
    uint4* x0c   = (uint4*)w; w += xSz;   // bf16 emb copy
    uint4* xa    = (uint4*)w; w += xSz;   // bf16 layer-1 x
    int* offsets = (int*)w; w += ((size_t)(N + 1) * 4 + 255) & ~(size_t)255;
    float* dis   = (float*)w; w += ((size_t)N * 4 + 255) & ~(size_t)255;
    int* outdeg  = (int*)w;               // N ints, zeroed
    int* bcnt    = outdeg + N;            // 1024 ints, zeroed (contiguous memset)
    w += ((size_t)(N + 1024) * 4 + 255) & ~(size_t)255;
    int* bucket_base = (int*)w; w += 1025 * 4;
    int* cursor      = (int*)w; w += 1024 * 4;

    const int TB = 256;
    hipMemsetAsync(outdeg, 0, (size_t)(N + 1024) * 4, stream);

    hist_src_kernel<<<RANGES * NSLICE, TBH, 0, stream>>>(src, dst, outdeg, bcnt,
                                                         E, N, Es, NB);
    dis_kernel<<<(N + TB - 1) / TB, TB, 0, stream>>>(outdeg, dis, N);
    scan_buckets<<<1, 1024, 0, stream>>>(bcnt, bucket_base, cursor, offsets, NB, N);
    part_kernel<<<(E + CH - 1) / CH, TB1, 0, stream>>>(src, dst, ew, cursor,
                                                       staged, E, NB);
    place_kernel<<<NB, TB, 0, stream>>>(staged, bucket_base, dis, offsets, csr, N);

    const int n8 = N * DIM / 8;
    conv_kernel<<<(n8 + TB - 1) / TB, TB, 0, stream>>>((const float4*)emb, x0c, n8);

    // 4 waves/block, 8 nodes/wave -> 32 nodes per block
    dim3 grid((N + 31) / 32), block(TB);
    prop_kernel<<<grid, block, 0, stream>>>(x0c, (const float4*)emb, xa,
                                            offsets, csr, dis, N,
                                            nullptr, nullptr, nullptr);
    prop_kernel<<<grid, block, 0, stream>>>(xa, nullptr, xb,
                                            offsets, csr, dis, N,
                                            nullptr, nullptr, nullptr);
    prop_kernel<<<grid, block, 0, stream>>>(xb, nullptr, nullptr,
                                            offsets, csr, dis, N,
                                            (const float4*)emb, xa, (float4*)out);
}